// Round 1
// baseline (1018.997 us; speedup 1.0000x reference)
//
#include <hip/hip_runtime.h>
#include <cstdint>
#include <cstddef>

#define NB   16
#define SEQ  4096
#define CC   512
#define NH   8
#define HD   64
#define NSPLIT 8

typedef _Float16 h8_t  __attribute__((ext_vector_type(8)));
typedef _Float16 h4_t  __attribute__((ext_vector_type(4)));
typedef float    f4_t  __attribute__((ext_vector_type(4)));

// ---------------- convert x (fp32 -> fp16) ----------------
__global__ __launch_bounds__(256) void cvt_x_kernel(const float* __restrict__ x,
                                                    _Float16* __restrict__ xh) {
    const int idx = blockIdx.x * 256 + threadIdx.x;      // 8388608 threads, 4 elems each
    const f4_t v = ((const f4_t*)x)[idx];
    h4_t o;
    o[0] = (_Float16)v[0]; o[1] = (_Float16)v[1];
    o[2] = (_Float16)v[2]; o[3] = (_Float16)v[3];
    ((h4_t*)xh)[idx] = o;
}

// ---------------- convert + transpose W (512x1024 -> Wt[1024][512] fp16) ----------------
__global__ __launch_bounds__(256) void cvt_w_kernel(const float* __restrict__ w,
                                                    _Float16* __restrict__ wt) {
    const int idx = blockIdx.x * 256 + threadIdx.x;      // 524288
    const int n = idx >> 9, k = idx & 511;
    wt[idx] = (_Float16)w[k * 1024 + n];
}

// ---------------- rope tables: ang[i][j] = i * theta_j, i<64, j<128 ----------------
__global__ __launch_bounds__(256) void rope_tables_kernel(float* __restrict__ ctab,
                                                          float* __restrict__ stab) {
    const int idx = blockIdx.x * 256 + threadIdx.x;      // 8192
    const int i = idx >> 7, j = idx & 127;
    const float theta = expf(-(float)j * (9.2103403719761836f / 128.f)); // 10000^(-j/128)
    const float ang = (float)i * theta;
    ctab[idx] = cosf(ang);
    stab[idx] = sinf(ang);
}

// ---------------- GEMM: qk = x @ W + bias, epilogue elu+1, split q/k ----------------
// A = xh [65536][512] fp16, B^T = wt [1024][512] fp16
__global__ __launch_bounds__(256) void gemm_qk(const _Float16* __restrict__ xh,
                                               const _Float16* __restrict__ wt,
                                               const float* __restrict__ bias,
                                               _Float16* __restrict__ qpre,
                                               _Float16* __restrict__ kpre) {
    __shared__ _Float16 As[128][40];   // +8 pad
    __shared__ _Float16 Bs[128][40];
    const int tid  = threadIdx.x;
    const int wave = tid >> 6, lane = tid & 63;
    const int bm = blockIdx.x, bn = blockIdx.y;
    const int wm = (wave >> 1) * 64, wn = (wave & 1) * 64;
    const int lr = tid >> 2, lk = (tid & 3) * 8;
    const int fr = lane & 15, fk = (lane >> 4) * 8;

    f4_t acc[4][4] = {};

    for (int k0 = 0; k0 < CC; k0 += 32) {
        *(h8_t*)&As[lr][lk]      = *(const h8_t*)&xh[(size_t)(bm * 128 + lr) * CC + k0 + lk];
        *(h8_t*)&As[lr + 64][lk] = *(const h8_t*)&xh[(size_t)(bm * 128 + 64 + lr) * CC + k0 + lk];
        *(h8_t*)&Bs[lr][lk]      = *(const h8_t*)&wt[(size_t)(bn * 128 + lr) * CC + k0 + lk];
        *(h8_t*)&Bs[lr + 64][lk] = *(const h8_t*)&wt[(size_t)(bn * 128 + 64 + lr) * CC + k0 + lk];
        __syncthreads();
        h8_t af[4], bf[4];
#pragma unroll
        for (int mi = 0; mi < 4; mi++) af[mi] = *(const h8_t*)&As[wm + mi * 16 + fr][fk];
#pragma unroll
        for (int ni = 0; ni < 4; ni++) bf[ni] = *(const h8_t*)&Bs[wn + ni * 16 + fr][fk];
#pragma unroll
        for (int mi = 0; mi < 4; mi++)
#pragma unroll
            for (int ni = 0; ni < 4; ni++)
                acc[mi][ni] = __builtin_amdgcn_mfma_f32_16x16x32_f16(af[mi], bf[ni], acc[mi][ni], 0, 0, 0);
        __syncthreads();
    }

    const int r4 = (lane >> 4) * 4;
#pragma unroll
    for (int ni = 0; ni < 4; ni++) {
        const int col = bn * 128 + wn + ni * 16 + fr;
        const float bc = bias[col];
#pragma unroll
        for (int mi = 0; mi < 4; mi++) {
#pragma unroll
            for (int r = 0; r < 4; r++) {
                const int row = bm * 128 + wm + mi * 16 + r4 + r;
                float v = acc[mi][ni][r] + bc;
                v = v > 0.f ? v + 1.f : __expf(v);      // elu(v)+1
                if (col < CC) qpre[(size_t)row * CC + col] = (_Float16)v;
                else          kpre[(size_t)row * CC + col - CC] = (_Float16)v;
            }
        }
    }
}

// ---------------- ksum[b][h][d] = sum_n k_pre ----------------
__global__ __launch_bounds__(256) void ksum_kernel(const _Float16* __restrict__ kpre,
                                                   float* __restrict__ ksum) {
    const int bh = blockIdx.x;                 // b*8+h
    const int b = bh >> 3, h = bh & 7;
    const int t = threadIdx.x;
    const int ch = t & 63, ng = t >> 6;
    const _Float16* base = kpre + (size_t)b * SEQ * CC + h * HD + ch;
    float s = 0.f;
    for (int n = ng; n < SEQ; n += 4) s += (float)base[(size_t)n * CC];
    __shared__ float red[4][64];
    red[ng][ch] = s;
    __syncthreads();
    if (t < 64) ksum[bh * HD + t] = red[0][t] + red[1][t] + red[2][t] + red[3][t];
}

// ---------------- kv[b][h][d][e] = (1/4096) sum_n k_rope[n][d] * v[n][e] ----------------
__global__ __launch_bounds__(256) void kv_kernel(const _Float16* __restrict__ kpre,
                                                 const float* __restrict__ x,
                                                 const float* __restrict__ ctab,
                                                 const float* __restrict__ stab,
                                                 float* __restrict__ kv) {
    const int blk = blockIdx.x;
    const int s = blk & (NSPLIT - 1);
    const int bh = blk / NSPLIT;
    const int b = bh >> 3, h = bh & 7;
    const int t = threadIdx.x;
    __shared__ float ks[64][68];
    __shared__ float vs[64][68];
    const int nn = t >> 2, ch0 = (t & 3) * 16;
    const int pbase = h * 32 + (ch0 >> 1);
    const bool rowrope = (pbase < 128);
    const int jbase = pbase & 127;
    const int d_own = t >> 2, e0 = (t & 3) * 16;

    float acc[16];
#pragma unroll
    for (int i = 0; i < 16; i++) acc[i] = 0.f;

    for (int c0 = 0; c0 < SEQ / NSPLIT; c0 += 64) {
        const int n = s * (SEQ / NSPLIT) + c0 + nn;
        const int ri = n >> 6, ci = n & 63;
        const int ii = rowrope ? ri : ci;
        const float* ct = ctab + ii * 128 + jbase;
        const float* st = stab + ii * 128 + jbase;
        const _Float16* kp = kpre + (size_t)(b * SEQ + n) * CC + h * HD + ch0;
        h8_t ka = *(const h8_t*)kp;
        h8_t kb = *(const h8_t*)(kp + 8);
#pragma unroll
        for (int i = 0; i < 4; i++) {
            float xr = (float)ka[2 * i], xi = (float)ka[2 * i + 1];
            float cv = ct[i], sv = st[i];
            ks[nn][ch0 + 2 * i]     = xr * cv - xi * sv;
            ks[nn][ch0 + 2 * i + 1] = xr * sv + xi * cv;
        }
#pragma unroll
        for (int i = 0; i < 4; i++) {
            float xr = (float)kb[2 * i], xi = (float)kb[2 * i + 1];
            float cv = ct[4 + i], sv = st[4 + i];
            ks[nn][ch0 + 8 + 2 * i]     = xr * cv - xi * sv;
            ks[nn][ch0 + 8 + 2 * i + 1] = xr * sv + xi * cv;
        }
        const float* xp = x + (size_t)(b * SEQ + n) * CC + h * HD + ch0;
#pragma unroll
        for (int i = 0; i < 4; i++) *(f4_t*)&vs[nn][ch0 + 4 * i] = *(const f4_t*)(xp + 4 * i);
        __syncthreads();
#pragma unroll 4
        for (int n2 = 0; n2 < 64; n2++) {
            const float kval = ks[n2][d_own];
#pragma unroll
            for (int i = 0; i < 16; i++) acc[i] += kval * vs[n2][e0 + i];
        }
        __syncthreads();
    }
    float* kvp = kv + ((size_t)bh * HD + d_own) * HD + e0;
#pragma unroll
    for (int i = 0; i < 16; i++) atomicAdd(kvp + i, acc[i] * (1.f / 4096.f));
}

// ---------------- out = z * (q_rope @ kv) + depthwise3x3(x) + lepe_bias ----------------
__global__ __launch_bounds__(256) void out_kernel(const _Float16* __restrict__ qpre,
                                                  const float* __restrict__ x,
                                                  const float* __restrict__ ctab,
                                                  const float* __restrict__ stab,
                                                  const float* __restrict__ kv,
                                                  const float* __restrict__ ksum,
                                                  const float* __restrict__ lw,
                                                  const float* __restrict__ lb,
                                                  float* __restrict__ out) {
    const int blk = blockIdx.x;
    const int rg = blk & 7;
    const int bh = blk >> 3;
    const int b = bh >> 3, h = bh & 7;
    const int t = threadIdx.x;

    __shared__ float kvs[64][68];
    __shared__ float qs[64][68];
    __shared__ float Sred[64][4];
    __shared__ float zs[64];
    __shared__ float ksums[64];
    __shared__ float wsh[9 * 64];
    __shared__ float lbs[64];

    const int dd = t >> 2, e0 = (t & 3) * 16;

    {
        const float* kvp = kv + ((size_t)bh * HD + dd) * HD + e0;
#pragma unroll
        for (int i = 0; i < 4; i++) *(f4_t*)&kvs[dd][e0 + 4 * i] = *(const f4_t*)(kvp + 4 * i);
    }
    if (t < 64) { ksums[t] = ksum[bh * HD + t]; lbs[t] = lb[h * HD + t]; }
    for (int i = t; i < 576; i += 256) wsh[i] = lw[(i >> 6) * CC + h * HD + (i & 63)];
    __syncthreads();

    const int pbase = h * 32 + (e0 >> 1);
    const bool rowrope = (pbase < 128);
    const int jbase = pbase & 127;

    for (int c0 = 0; c0 < 512; c0 += 64) {
        const int pix = rg * 512 + c0 + dd;
        const int ri = pix >> 6, ci = pix & 63;
        {   // stage q_rope + S partial
            const int ii = rowrope ? ri : ci;
            const float* ct = ctab + ii * 128 + jbase;
            const float* st = stab + ii * 128 + jbase;
            const _Float16* qp = qpre + (size_t)(b * SEQ + pix) * CC + h * HD + e0;
            h8_t qa = *(const h8_t*)qp;
            h8_t qb = *(const h8_t*)(qp + 8);
            float Sp = 0.f;
#pragma unroll
            for (int i = 0; i < 4; i++) {
                float xr = (float)qa[2 * i], xi = (float)qa[2 * i + 1];
                float cv = ct[i], sv = st[i];
                qs[dd][e0 + 2 * i]     = xr * cv - xi * sv;
                qs[dd][e0 + 2 * i + 1] = xr * sv + xi * cv;
                Sp += xr * ksums[e0 + 2 * i] + xi * ksums[e0 + 2 * i + 1];
            }
#pragma unroll
            for (int i = 0; i < 4; i++) {
                float xr = (float)qb[2 * i], xi = (float)qb[2 * i + 1];
                float cv = ct[4 + i], sv = st[4 + i];
                qs[dd][e0 + 8 + 2 * i]     = xr * cv - xi * sv;
                qs[dd][e0 + 8 + 2 * i + 1] = xr * sv + xi * cv;
                Sp += xr * ksums[e0 + 8 + 2 * i] + xi * ksums[e0 + 8 + 2 * i + 1];
            }
            Sred[dd][t & 3] = Sp;
        }
        __syncthreads();
        if (t < 64) {
            float S = (Sred[t][0] + Sred[t][1] + Sred[t][2] + Sred[t][3]) * (1.f / 4096.f);
            zs[t] = 1.f / (S + 1e-6f);
        }
        __syncthreads();

        float acc[16];
#pragma unroll
        for (int i = 0; i < 16; i++) acc[i] = 0.f;
#pragma unroll 4
        for (int d = 0; d < 64; d++) {
            const float qv = qs[dd][d];
#pragma unroll
            for (int i = 0; i < 16; i++) acc[i] += qv * kvs[d][e0 + i];
        }

        float cacc[16];
#pragma unroll
        for (int i = 0; i < 16; i++) cacc[i] = 0.f;
#pragma unroll
        for (int dr = -1; dr <= 1; dr++) {
            const int rr = ri + dr;
            if (rr < 0 || rr >= 64) continue;
#pragma unroll
            for (int dc = -1; dc <= 1; dc++) {
                const int cc2 = ci + dc;
                if (cc2 < 0 || cc2 >= 64) continue;
                const float* xp = x + (size_t)(b * SEQ + rr * 64 + cc2) * CC + h * HD + e0;
                const float* wp = wsh + ((dr + 1) * 3 + (dc + 1)) * 64 + e0;
#pragma unroll
                for (int i = 0; i < 16; i++) cacc[i] += xp[i] * wp[i];
            }
        }
        const float z = zs[dd];
        float* op = out + (size_t)(b * SEQ + pix) * CC + h * HD + e0;
#pragma unroll
        for (int i = 0; i < 16; i++) op[i] = z * acc[i] + cacc[i] + lbs[e0 + i];
        __syncthreads();
    }
}

extern "C" void kernel_launch(void* const* d_in, const int* in_sizes, int n_in,
                              void* d_out, int out_size, void* d_ws, size_t ws_size,
                              hipStream_t stream) {
    const float* x      = (const float*)d_in[0];
    const float* qk_w   = (const float*)d_in[1];
    const float* qk_b   = (const float*)d_in[2];
    const float* lepe_w = (const float*)d_in[3];
    const float* lepe_b = (const float*)d_in[4];
    float* out = (float*)d_out;

    char* ws = (char*)d_ws;
    size_t off = 0;
    auto alloc = [&](size_t bytes) {
        void* p = ws + off;
        off += (bytes + 255) & ~(size_t)255;
        return p;
    };
    _Float16* xh   = (_Float16*)alloc((size_t)NB * SEQ * CC * 2);
    _Float16* wt   = (_Float16*)alloc((size_t)1024 * 512 * 2);
    _Float16* qpre = (_Float16*)alloc((size_t)NB * SEQ * CC * 2);
    _Float16* kpre = (_Float16*)alloc((size_t)NB * SEQ * CC * 2);
    float* kv      = (float*)alloc((size_t)NB * NH * HD * HD * 4);
    float* ksum    = (float*)alloc((size_t)NB * NH * HD * 4);
    float* ctab    = (float*)alloc(64 * 128 * 4);
    float* stab    = (float*)alloc(64 * 128 * 4);

    hipMemsetAsync(kv, 0, (size_t)NB * NH * HD * HD * 4, stream);
    cvt_x_kernel<<<32768, 256, 0, stream>>>(x, xh);
    cvt_w_kernel<<<2048, 256, 0, stream>>>(qk_w, wt);
    rope_tables_kernel<<<32, 256, 0, stream>>>(ctab, stab);
    gemm_qk<<<dim3(512, 8), 256, 0, stream>>>(xh, wt, qk_b, qpre, kpre);
    ksum_kernel<<<128, 256, 0, stream>>>(kpre, ksum);
    kv_kernel<<<NB * NH * NSPLIT, 256, 0, stream>>>(kpre, x, ctab, stab, kv);
    out_kernel<<<NB * NH * 8, 256, 0, stream>>>(qpre, x, ctab, stab, kv, ksum, lepe_w, lepe_b, out);
}

// Round 2
// 747.250 us; speedup vs baseline: 1.3637x; 1.3637x over previous
//
#include <hip/hip_runtime.h>
#include <cstdint>
#include <cstddef>

#define NB   16
#define SEQ  4096
#define CC   512
#define NH   8
#define HD   64
#define NSPLIT 8

typedef _Float16 h8_t  __attribute__((ext_vector_type(8)));
typedef _Float16 h4_t  __attribute__((ext_vector_type(4)));
typedef float    f4_t  __attribute__((ext_vector_type(4)));

typedef __attribute__((address_space(1))) const void gv_t;
typedef __attribute__((address_space(3))) void lv_t;

__device__ __forceinline__ void gload16(const void* g, void* l) {
    __builtin_amdgcn_global_load_lds((gv_t*)g, (lv_t*)l, 16, 0, 0);
}

// ---------------- convert x (fp32 -> fp16) ----------------
__global__ __launch_bounds__(256) void cvt_x_kernel(const float* __restrict__ x,
                                                    _Float16* __restrict__ xh) {
    const int idx = blockIdx.x * 256 + threadIdx.x;      // 8388608 threads, 4 elems each
    const f4_t v = ((const f4_t*)x)[idx];
    h4_t o;
    o[0] = (_Float16)v[0]; o[1] = (_Float16)v[1];
    o[2] = (_Float16)v[2]; o[3] = (_Float16)v[3];
    ((h4_t*)xh)[idx] = o;
}

// ---------------- convert + transpose W (512x1024 -> Wt[1024][512] fp16) ----------------
__global__ __launch_bounds__(256) void cvt_w_kernel(const float* __restrict__ w,
                                                    _Float16* __restrict__ wt) {
    const int idx = blockIdx.x * 256 + threadIdx.x;      // 524288
    const int n = idx >> 9, k = idx & 511;
    wt[idx] = (_Float16)w[k * 1024 + n];
}

// ---------------- rope tables: ang[i][j] = i * theta_j, i<64, j<128 ----------------
__global__ __launch_bounds__(256) void rope_tables_kernel(float* __restrict__ ctab,
                                                          float* __restrict__ stab) {
    const int idx = blockIdx.x * 256 + threadIdx.x;      // 8192
    const int i = idx >> 7, j = idx & 127;
    const float theta = expf(-(float)j * (9.2103403719761836f / 128.f)); // 10000^(-j/128)
    const float ang = (float)i * theta;
    ctab[idx] = cosf(ang);
    stab[idx] = sinf(ang);
}

// ---------------- GEMM: qk = x @ W + bias, epilogue elu+1, split q/k ----------------
// A = xh [65536][512] fp16, B^T = wt [1024][512] fp16
// m97 structure: 128x128 tile, BK=32, linear LDS, global_load_lds width 16.
__global__ __launch_bounds__(256) void gemm_qk(const _Float16* __restrict__ xh,
                                               const _Float16* __restrict__ wt,
                                               const float* __restrict__ bias,
                                               _Float16* __restrict__ qpre,
                                               _Float16* __restrict__ kpre) {
    __shared__ _Float16 smem[2 * 128 * 32];        // As | Bs, linear (no pad: gload_lds dest)
    _Float16* As = smem;
    _Float16* Bs = smem + 128 * 32;

    const int tid  = threadIdx.x;
    const int wave = tid >> 6, lane = tid & 63;
    const int bn = blockIdx.x, bm = blockIdx.y;    // bn fast: consecutive blocks share A-panel
    const int wm = (wave >> 1) * 64, wn = (wave & 1) * 64;
    const int fr = lane & 15, fk = (lane >> 4) * 8;

    // staging geometry: chunk = 16 rows x 32 cols = 1024B = 64 lanes * 16B
    const int c0 = wave * 2;
    const int srow = c0 * 16 + (lane >> 2);
    const int scol = (lane & 3) * 8;

    const _Float16* agp0 = xh + (size_t)(bm * 128 + srow) * CC + scol;
    const _Float16* agp1 = agp0 + (size_t)16 * CC;
    const _Float16* bgp0 = wt + (size_t)(bn * 128 + srow) * CC + scol;
    const _Float16* bgp1 = bgp0 + (size_t)16 * CC;
    _Float16* alds0 = As + c0 * 512;               // 512 fp16 = 1024B per chunk
    _Float16* alds1 = As + (c0 + 1) * 512;
    _Float16* blds0 = Bs + c0 * 512;
    _Float16* blds1 = Bs + (c0 + 1) * 512;

    f4_t acc[4][4] = {};

    for (int k0 = 0; k0 < CC; k0 += 32) {
        gload16(agp0 + k0, alds0);
        gload16(agp1 + k0, alds1);
        gload16(bgp0 + k0, blds0);
        gload16(bgp1 + k0, blds1);
        __syncthreads();
        h8_t af[4], bf[4];
#pragma unroll
        for (int mi = 0; mi < 4; mi++) af[mi] = *(const h8_t*)&As[(wm + mi * 16 + fr) * 32 + fk];
#pragma unroll
        for (int ni = 0; ni < 4; ni++) bf[ni] = *(const h8_t*)&Bs[(wn + ni * 16 + fr) * 32 + fk];
#pragma unroll
        for (int mi = 0; mi < 4; mi++)
#pragma unroll
            for (int ni = 0; ni < 4; ni++)
                acc[mi][ni] = __builtin_amdgcn_mfma_f32_16x16x32_f16(af[mi], bf[ni], acc[mi][ni], 0, 0, 0);
        __syncthreads();
    }

    const int r4 = (lane >> 4) * 4;
#pragma unroll
    for (int ni = 0; ni < 4; ni++) {
        const int col = bn * 128 + wn + ni * 16 + fr;
        const float bc = bias[col];
#pragma unroll
        for (int mi = 0; mi < 4; mi++) {
#pragma unroll
            for (int r = 0; r < 4; r++) {
                const int row = bm * 128 + wm + mi * 16 + r4 + r;
                float v = acc[mi][ni][r] + bc;
                v = v > 0.f ? v + 1.f : __expf(v);      // elu(v)+1
                if (col < CC) qpre[(size_t)row * CC + col] = (_Float16)v;
                else          kpre[(size_t)row * CC + col - CC] = (_Float16)v;
            }
        }
    }
}

// ---------------- kv[b][h][d][e] = (1/4096) sum_n k_rope[n][d] * v[n][e] ----------------
// fused: ksum[b][h][d] = sum_n k_pre[n][d]  (pre-rope, raw sum; out_kernel scales by 1/4096)
__global__ __launch_bounds__(256) void kv_kernel(const _Float16* __restrict__ kpre,
                                                 const _Float16* __restrict__ xh,
                                                 const float* __restrict__ ctab,
                                                 const float* __restrict__ stab,
                                                 float* __restrict__ kv,
                                                 float* __restrict__ ksum) {
    const int blk = blockIdx.x;
    const int s = blk & (NSPLIT - 1);
    const int bh = blk / NSPLIT;
    const int b = bh >> 3, h = bh & 7;
    const int t = threadIdx.x;
    __shared__ float ks[64][68];
    __shared__ float vs[64][68];
    const int nn = t >> 2, ch0 = (t & 3) * 16;
    const int pbase = h * 32 + (ch0 >> 1);
    const bool rowrope = (pbase < 128);
    const int jbase = pbase & 127;
    const int d_own = t >> 2, e0 = (t & 3) * 16;

    float acc[16];
    float ksp[16];
#pragma unroll
    for (int i = 0; i < 16; i++) { acc[i] = 0.f; ksp[i] = 0.f; }

    for (int c0 = 0; c0 < SEQ / NSPLIT; c0 += 64) {
        const int n = s * (SEQ / NSPLIT) + c0 + nn;
        const int ri = n >> 6, ci = n & 63;
        const int ii = rowrope ? ri : ci;
        const float* ct = ctab + ii * 128 + jbase;
        const float* st = stab + ii * 128 + jbase;
        const _Float16* kp = kpre + (size_t)(b * SEQ + n) * CC + h * HD + ch0;
        h8_t ka = *(const h8_t*)kp;
        h8_t kb = *(const h8_t*)(kp + 8);
#pragma unroll
        for (int i = 0; i < 8; i++) { ksp[i] += (float)ka[i]; ksp[8 + i] += (float)kb[i]; }
#pragma unroll
        for (int i = 0; i < 4; i++) {
            float xr = (float)ka[2 * i], xi = (float)ka[2 * i + 1];
            float cv = ct[i], sv = st[i];
            ks[nn][ch0 + 2 * i]     = xr * cv - xi * sv;
            ks[nn][ch0 + 2 * i + 1] = xr * sv + xi * cv;
        }
#pragma unroll
        for (int i = 0; i < 4; i++) {
            float xr = (float)kb[2 * i], xi = (float)kb[2 * i + 1];
            float cv = ct[4 + i], sv = st[4 + i];
            ks[nn][ch0 + 8 + 2 * i]     = xr * cv - xi * sv;
            ks[nn][ch0 + 8 + 2 * i + 1] = xr * sv + xi * cv;
        }
        const _Float16* xp = xh + (size_t)(b * SEQ + n) * CC + h * HD + ch0;
        h8_t va = *(const h8_t*)xp;
        h8_t vb = *(const h8_t*)(xp + 8);
#pragma unroll
        for (int i = 0; i < 8; i++) { vs[nn][ch0 + i] = (float)va[i]; vs[nn][ch0 + 8 + i] = (float)vb[i]; }
        __syncthreads();
#pragma unroll 4
        for (int n2 = 0; n2 < 64; n2++) {
            const float kval = ks[n2][d_own];
#pragma unroll
            for (int i = 0; i < 16; i++) acc[i] += kval * vs[n2][e0 + i];
        }
        __syncthreads();
    }
    float* kvp = kv + ((size_t)bh * HD + d_own) * HD + e0;
#pragma unroll
    for (int i = 0; i < 16; i++) atomicAdd(kvp + i, acc[i] * (1.f / 4096.f));

    // block-level ksum reduction (reuse vs)
#pragma unroll
    for (int i = 0; i < 16; i++) vs[nn][ch0 + i] = ksp[i];
    __syncthreads();
    if (t < 64) {
        float sum = 0.f;
        for (int n2 = 0; n2 < 64; n2++) sum += vs[n2][t];
        atomicAdd(&ksum[bh * HD + t], sum);
    }
}

// ---------------- out = z * (q_rope @ kv) + depthwise3x3(v) + lepe_bias ----------------
__global__ __launch_bounds__(256) void out_kernel(const _Float16* __restrict__ qpre,
                                                  const _Float16* __restrict__ xh,
                                                  const float* __restrict__ ctab,
                                                  const float* __restrict__ stab,
                                                  const float* __restrict__ kv,
                                                  const float* __restrict__ ksum,
                                                  const float* __restrict__ lw,
                                                  const float* __restrict__ lb,
                                                  float* __restrict__ out) {
    const int blk = blockIdx.x;
    const int rg = blk & 7;
    const int bh = blk >> 3;
    const int b = bh >> 3, h = bh & 7;
    const int t = threadIdx.x;

    __shared__ float kvs[64][68];
    __shared__ float qs[64][68];
    __shared__ float Sred[64][4];
    __shared__ float zs[64];
    __shared__ float ksums[64];
    __shared__ float wsh[9 * 64];
    __shared__ float lbs[64];

    const int dd = t >> 2, e0 = (t & 3) * 16;

    {
        const float* kvp = kv + ((size_t)bh * HD + dd) * HD + e0;
#pragma unroll
        for (int i = 0; i < 4; i++) *(f4_t*)&kvs[dd][e0 + 4 * i] = *(const f4_t*)(kvp + 4 * i);
    }
    if (t < 64) { ksums[t] = ksum[bh * HD + t]; lbs[t] = lb[h * HD + t]; }
    for (int i = t; i < 576; i += 256) wsh[i] = lw[(i >> 6) * CC + h * HD + (i & 63)];
    __syncthreads();

    const int pbase = h * 32 + (e0 >> 1);
    const bool rowrope = (pbase < 128);
    const int jbase = pbase & 127;

    for (int c0 = 0; c0 < 512; c0 += 64) {
        const int pix = rg * 512 + c0 + dd;
        const int ri = pix >> 6, ci = pix & 63;
        {   // stage q_rope + S partial
            const int ii = rowrope ? ri : ci;
            const float* ct = ctab + ii * 128 + jbase;
            const float* st = stab + ii * 128 + jbase;
            const _Float16* qp = qpre + (size_t)(b * SEQ + pix) * CC + h * HD + e0;
            h8_t qa = *(const h8_t*)qp;
            h8_t qb = *(const h8_t*)(qp + 8);
            float Sp = 0.f;
#pragma unroll
            for (int i = 0; i < 4; i++) {
                float xr = (float)qa[2 * i], xi = (float)qa[2 * i + 1];
                float cv = ct[i], sv = st[i];
                qs[dd][e0 + 2 * i]     = xr * cv - xi * sv;
                qs[dd][e0 + 2 * i + 1] = xr * sv + xi * cv;
                Sp += xr * ksums[e0 + 2 * i] + xi * ksums[e0 + 2 * i + 1];
            }
#pragma unroll
            for (int i = 0; i < 4; i++) {
                float xr = (float)qb[2 * i], xi = (float)qb[2 * i + 1];
                float cv = ct[4 + i], sv = st[4 + i];
                qs[dd][e0 + 8 + 2 * i]     = xr * cv - xi * sv;
                qs[dd][e0 + 8 + 2 * i + 1] = xr * sv + xi * cv;
                Sp += xr * ksums[e0 + 8 + 2 * i] + xi * ksums[e0 + 8 + 2 * i + 1];
            }
            Sred[dd][t & 3] = Sp;
        }
        __syncthreads();
        if (t < 64) {
            float S = (Sred[t][0] + Sred[t][1] + Sred[t][2] + Sred[t][3]) * (1.f / 4096.f);
            zs[t] = 1.f / (S + 1e-6f);
        }
        __syncthreads();

        float acc[16];
#pragma unroll
        for (int i = 0; i < 16; i++) acc[i] = 0.f;
#pragma unroll 4
        for (int d = 0; d < 64; d++) {
            const float qv = qs[dd][d];
#pragma unroll
            for (int i = 0; i < 16; i++) acc[i] += qv * kvs[d][e0 + i];
        }

        float cacc[16];
#pragma unroll
        for (int i = 0; i < 16; i++) cacc[i] = 0.f;
#pragma unroll
        for (int dr = -1; dr <= 1; dr++) {
            const int rr = ri + dr;
            if (rr < 0 || rr >= 64) continue;
#pragma unroll
            for (int dc = -1; dc <= 1; dc++) {
                const int cc2 = ci + dc;
                if (cc2 < 0 || cc2 >= 64) continue;
                const _Float16* xp = xh + (size_t)(b * SEQ + rr * 64 + cc2) * CC + h * HD + e0;
                const float* wp = wsh + ((dr + 1) * 3 + (dc + 1)) * 64 + e0;
                h8_t xa = *(const h8_t*)xp;
                h8_t xb = *(const h8_t*)(xp + 8);
#pragma unroll
                for (int i = 0; i < 8; i++) {
                    cacc[i]     += (float)xa[i] * wp[i];
                    cacc[8 + i] += (float)xb[i] * wp[8 + i];
                }
            }
        }
        const float z = zs[dd];
        float* op = out + (size_t)(b * SEQ + pix) * CC + h * HD + e0;
#pragma unroll
        for (int i = 0; i < 16; i++) op[i] = z * acc[i] + cacc[i] + lbs[e0 + i];
        __syncthreads();
    }
}

extern "C" void kernel_launch(void* const* d_in, const int* in_sizes, int n_in,
                              void* d_out, int out_size, void* d_ws, size_t ws_size,
                              hipStream_t stream) {
    const float* x      = (const float*)d_in[0];
    const float* qk_w   = (const float*)d_in[1];
    const float* qk_b   = (const float*)d_in[2];
    const float* lepe_w = (const float*)d_in[3];
    const float* lepe_b = (const float*)d_in[4];
    float* out = (float*)d_out;

    char* ws = (char*)d_ws;
    size_t off = 0;
    auto alloc = [&](size_t bytes) {
        void* p = ws + off;
        off += (bytes + 255) & ~(size_t)255;
        return p;
    };
    _Float16* xh   = (_Float16*)alloc((size_t)NB * SEQ * CC * 2);
    _Float16* wt   = (_Float16*)alloc((size_t)1024 * 512 * 2);
    _Float16* qpre = (_Float16*)alloc((size_t)NB * SEQ * CC * 2);
    _Float16* kpre = (_Float16*)alloc((size_t)NB * SEQ * CC * 2);
    float* kv      = (float*)alloc((size_t)NB * NH * HD * HD * 4);
    float* ksum    = (float*)alloc((size_t)NB * NH * HD * 4);
    float* ctab    = (float*)alloc(64 * 128 * 4);
    float* stab    = (float*)alloc(64 * 128 * 4);

    // kv + ksum are contiguous in ws: single memset covers both
    hipMemsetAsync(kv, 0, (size_t)NB * NH * HD * HD * 4 + ((size_t)NB * NH * HD * 4 + 255 & ~(size_t)255), stream);
    cvt_x_kernel<<<32768, 256, 0, stream>>>(x, xh);
    cvt_w_kernel<<<2048, 256, 0, stream>>>(qk_w, wt);
    rope_tables_kernel<<<32, 256, 0, stream>>>(ctab, stab);
    gemm_qk<<<dim3(8, 512), 256, 0, stream>>>(xh, wt, qk_b, qpre, kpre);
    kv_kernel<<<NB * NH * NSPLIT, 256, 0, stream>>>(kpre, xh, ctab, stab, kv, ksum);
    out_kernel<<<NB * NH * 8, 256, 0, stream>>>(qpre, xh, ctab, stab, kv, ksum, lepe_w, lepe_b, out);
}

// Round 3
// 499.265 us; speedup vs baseline: 2.0410x; 1.4967x over previous
//
#include <hip/hip_runtime.h>
#include <cstdint>
#include <cstddef>

#define NB   16
#define SEQ  4096
#define CC   512
#define NH   8
#define HD   64
#define NSPLIT 8

typedef _Float16 h8_t  __attribute__((ext_vector_type(8)));
typedef _Float16 h4_t  __attribute__((ext_vector_type(4)));
typedef float    f4_t  __attribute__((ext_vector_type(4)));

typedef __attribute__((address_space(1))) const void gv_t;
typedef __attribute__((address_space(3))) void lv_t;

__device__ __forceinline__ void gload16(const void* g, void* l) {
    __builtin_amdgcn_global_load_lds((gv_t*)g, (lv_t*)l, 16, 0, 0);
}

// ---------------- convert x (fp32 -> fp16) ----------------
__global__ __launch_bounds__(256) void cvt_x_kernel(const float* __restrict__ x,
                                                    _Float16* __restrict__ xh) {
    const int idx = blockIdx.x * 256 + threadIdx.x;      // 8388608 threads, 4 elems each
    const f4_t v = ((const f4_t*)x)[idx];
    h4_t o;
    o[0] = (_Float16)v[0]; o[1] = (_Float16)v[1];
    o[2] = (_Float16)v[2]; o[3] = (_Float16)v[3];
    ((h4_t*)xh)[idx] = o;
}

// ---------------- convert + transpose W (512x1024 -> Wt[1024][512] fp16) ----------------
__global__ __launch_bounds__(256) void cvt_w_kernel(const float* __restrict__ w,
                                                    _Float16* __restrict__ wt) {
    const int idx = blockIdx.x * 256 + threadIdx.x;      // 524288
    const int n = idx >> 9, k = idx & 511;
    wt[idx] = (_Float16)w[k * 1024 + n];
}

// ---------------- rope tables: ang[i][j] = i * theta_j, i<64, j<128 ----------------
__global__ __launch_bounds__(256) void rope_tables_kernel(float* __restrict__ ctab,
                                                          float* __restrict__ stab) {
    const int idx = blockIdx.x * 256 + threadIdx.x;      // 8192
    const int i = idx >> 7, j = idx & 127;
    const float theta = expf(-(float)j * (9.2103403719761836f / 128.f)); // 10000^(-j/128)
    const float ang = (float)i * theta;
    ctab[idx] = cosf(ang);
    stab[idx] = sinf(ang);
}

// ---------------- GEMM: qk = x @ W + bias, epilogue elu+1, split q/k ----------------
__global__ __launch_bounds__(256) void gemm_qk(const _Float16* __restrict__ xh,
                                               const _Float16* __restrict__ wt,
                                               const float* __restrict__ bias,
                                               _Float16* __restrict__ qpre,
                                               _Float16* __restrict__ kpre) {
    __shared__ _Float16 smem[2 * 128 * 32];        // As | Bs, linear (no pad: gload_lds dest)
    _Float16* As = smem;
    _Float16* Bs = smem + 128 * 32;

    const int tid  = threadIdx.x;
    const int wave = tid >> 6, lane = tid & 63;
    const int bn = blockIdx.x, bm = blockIdx.y;    // bn fast: consecutive blocks share A-panel
    const int wm = (wave >> 1) * 64, wn = (wave & 1) * 64;
    const int fr = lane & 15, fk = (lane >> 4) * 8;

    const int c0 = wave * 2;
    const int srow = c0 * 16 + (lane >> 2);
    const int scol = (lane & 3) * 8;

    const _Float16* agp0 = xh + (size_t)(bm * 128 + srow) * CC + scol;
    const _Float16* agp1 = agp0 + (size_t)16 * CC;
    const _Float16* bgp0 = wt + (size_t)(bn * 128 + srow) * CC + scol;
    const _Float16* bgp1 = bgp0 + (size_t)16 * CC;
    _Float16* alds0 = As + c0 * 512;
    _Float16* alds1 = As + (c0 + 1) * 512;
    _Float16* blds0 = Bs + c0 * 512;
    _Float16* blds1 = Bs + (c0 + 1) * 512;

    f4_t acc[4][4] = {};

    for (int k0 = 0; k0 < CC; k0 += 32) {
        gload16(agp0 + k0, alds0);
        gload16(agp1 + k0, alds1);
        gload16(bgp0 + k0, blds0);
        gload16(bgp1 + k0, blds1);
        __syncthreads();
        h8_t af[4], bf[4];
#pragma unroll
        for (int mi = 0; mi < 4; mi++) af[mi] = *(const h8_t*)&As[(wm + mi * 16 + fr) * 32 + fk];
#pragma unroll
        for (int ni = 0; ni < 4; ni++) bf[ni] = *(const h8_t*)&Bs[(wn + ni * 16 + fr) * 32 + fk];
#pragma unroll
        for (int mi = 0; mi < 4; mi++)
#pragma unroll
            for (int ni = 0; ni < 4; ni++)
                acc[mi][ni] = __builtin_amdgcn_mfma_f32_16x16x32_f16(af[mi], bf[ni], acc[mi][ni], 0, 0, 0);
        __syncthreads();
    }

    const int r4 = (lane >> 4) * 4;
#pragma unroll
    for (int ni = 0; ni < 4; ni++) {
        const int col = bn * 128 + wn + ni * 16 + fr;
        const float bc = bias[col];
#pragma unroll
        for (int mi = 0; mi < 4; mi++) {
#pragma unroll
            for (int r = 0; r < 4; r++) {
                const int row = bm * 128 + wm + mi * 16 + r4 + r;
                float v = acc[mi][ni][r] + bc;
                v = v > 0.f ? v + 1.f : __expf(v);      // elu(v)+1
                if (col < CC) qpre[(size_t)row * CC + col] = (_Float16)v;
                else          kpre[(size_t)row * CC + col - CC] = (_Float16)v;
            }
        }
    }
}

// ---------------- kv[b][h][d][e] = (1/4096) sum_n k_rope[n][d] * v[n][e]  (MFMA) ----------------
// also fused: ksum[b][h][d] = sum_n k_pre[n][d]
// LDS tiles channel-major: Kt[d][n], Vt[e][n], fp16, row pad 72 (144B rows -> b128-optimal banks).
__global__ __launch_bounds__(256) void kv_kernel(const _Float16* __restrict__ kpre,
                                                 const _Float16* __restrict__ xh,
                                                 const float* __restrict__ ctab,
                                                 const float* __restrict__ stab,
                                                 float* __restrict__ kv,
                                                 float* __restrict__ ksum) {
    const int blk = blockIdx.x;
    const int s = blk & (NSPLIT - 1);
    const int bh = blk / NSPLIT;
    const int b = bh >> 3, h = bh & 7;
    const int t = threadIdx.x;
    const int wave = t >> 6, lane = t & 63;

    __shared__ _Float16 Kt[64][72];
    __shared__ _Float16 Vt[64][72];

    const int nn  = lane;             // n within tile
    const int ch0 = wave * 16;        // channel block owned by this wave (stage + output d-rows)
    const int pbase = h * 32 + (ch0 >> 1);
    const bool rowrope = (pbase < 128);
    const int jbase = pbase & 127;
    const int fr = lane & 15, fk = (lane >> 4) * 8;

    f4_t acc[4] = {};
    float ksp[16];
#pragma unroll
    for (int i = 0; i < 16; i++) ksp[i] = 0.f;

    for (int c0 = 0; c0 < SEQ / NSPLIT; c0 += 64) {
        const int n = s * (SEQ / NSPLIT) + c0 + nn;
        const int ri = n >> 6, ci = n & 63;
        const int ii = rowrope ? ri : ci;
        const float* ct = ctab + ii * 128 + jbase;
        const float* st = stab + ii * 128 + jbase;

        const _Float16* kp = kpre + (size_t)(b * SEQ + n) * CC + h * HD + ch0;
        h8_t ka = *(const h8_t*)kp;
        h8_t kb = *(const h8_t*)(kp + 8);
#pragma unroll
        for (int i = 0; i < 8; i++) { ksp[i] += (float)ka[i]; ksp[8 + i] += (float)kb[i]; }
#pragma unroll
        for (int i = 0; i < 4; i++) {
            float xr = (float)ka[2 * i], xi = (float)ka[2 * i + 1];
            float cv = ct[i], sv = st[i];
            Kt[ch0 + 2 * i][nn]     = (_Float16)(xr * cv - xi * sv);
            Kt[ch0 + 2 * i + 1][nn] = (_Float16)(xr * sv + xi * cv);
        }
#pragma unroll
        for (int i = 0; i < 4; i++) {
            float xr = (float)kb[2 * i], xi = (float)kb[2 * i + 1];
            float cv = ct[4 + i], sv = st[4 + i];
            Kt[ch0 + 8 + 2 * i][nn]     = (_Float16)(xr * cv - xi * sv);
            Kt[ch0 + 8 + 2 * i + 1][nn] = (_Float16)(xr * sv + xi * cv);
        }
        const _Float16* xp = xh + (size_t)(b * SEQ + n) * CC + h * HD + ch0;
        h8_t va = *(const h8_t*)xp;
        h8_t vb = *(const h8_t*)(xp + 8);
#pragma unroll
        for (int i = 0; i < 8; i++) { Vt[ch0 + i][nn] = va[i]; Vt[ch0 + 8 + i][nn] = vb[i]; }
        __syncthreads();

#pragma unroll
        for (int k0 = 0; k0 < 64; k0 += 32) {
            h8_t af = *(const h8_t*)&Kt[ch0 + fr][k0 + fk];
#pragma unroll
            for (int et = 0; et < 4; et++) {
                h8_t bf = *(const h8_t*)&Vt[et * 16 + fr][k0 + fk];
                acc[et] = __builtin_amdgcn_mfma_f32_16x16x32_f16(af, bf, acc[et], 0, 0, 0);
            }
        }
        __syncthreads();
    }

    // epilogue: acc tile (rows d = ch0 + (lane>>4)*4+r, cols e = et*16 + (lane&15))
    const int col = lane & 15, r0 = (lane >> 4) * 4;
    float* kvbase = kv + (size_t)bh * HD * HD;
#pragma unroll
    for (int et = 0; et < 4; et++)
#pragma unroll
        for (int r = 0; r < 4; r++)
            atomicAdd(&kvbase[(ch0 + r0 + r) * HD + et * 16 + col], acc[et][r] * (1.f / 4096.f));

    // ksum: wave lanes cover all n of this split for channels ch0..ch0+15
#pragma unroll
    for (int i = 0; i < 16; i++) {
        float v = ksp[i];
#pragma unroll
        for (int m = 32; m; m >>= 1) v += __shfl_xor(v, m);
        if (lane == 0) atomicAdd(&ksum[bh * HD + ch0 + i], v);
    }
}

// ---------------- out = z * (q_rope @ kv) + depthwise3x3(v) + lepe_bias  (MFMA) ----------------
__global__ __launch_bounds__(256) void out_kernel(const _Float16* __restrict__ qpre,
                                                  const _Float16* __restrict__ xh,
                                                  const float* __restrict__ ctab,
                                                  const float* __restrict__ stab,
                                                  const float* __restrict__ kv,
                                                  const float* __restrict__ ksum,
                                                  const float* __restrict__ lw,
                                                  const float* __restrict__ lb,
                                                  float* __restrict__ out) {
    const int blk = blockIdx.x;
    const int rg = blk & 7;
    const int bh = blk >> 3;
    const int b = bh >> 3, h = bh & 7;
    const int t = threadIdx.x;
    const int wave = t >> 6, lane = t & 63;

    __shared__ _Float16 qs[64][72];    // q_rope tile, [n][d]
    __shared__ _Float16 kvt[64][72];   // kv^T, [e][d]
    __shared__ _Float16 attn[64][72];  // z * (q_rope @ kv), [n][e]
    __shared__ float Sred[64][4];
    __shared__ float zs[64];
    __shared__ float ksums[64];
    __shared__ float wsh[9 * 64];
    __shared__ float lbs[64];

    const int dd = t >> 2, e0 = (t & 3) * 16;
    const int fr = lane & 15, fk = (lane >> 4) * 8;

    {   // stage kv^T (fp16) once
        const float* kvp = kv + ((size_t)bh * HD + dd) * HD + e0;
#pragma unroll
        for (int i = 0; i < 16; i++) kvt[e0 + i][dd] = (_Float16)kvp[i];
    }
    if (t < 64) { ksums[t] = ksum[bh * HD + t]; lbs[t] = lb[h * HD + t]; }
    for (int i = t; i < 576; i += 256) wsh[i] = lw[(i >> 6) * CC + h * HD + (i & 63)];
    __syncthreads();

    const int pbase = h * 32 + (e0 >> 1);
    const bool rowrope = (pbase < 128);
    const int jbase = pbase & 127;

    for (int c0 = 0; c0 < 512; c0 += 64) {
        const int pix = rg * 512 + c0 + dd;
        const int ri = pix >> 6, ci = pix & 63;
        {   // stage q_rope (fp16, row-major) + S partial
            const int ii = rowrope ? ri : ci;
            const float* ct = ctab + ii * 128 + jbase;
            const float* st = stab + ii * 128 + jbase;
            const _Float16* qp = qpre + (size_t)(b * SEQ + pix) * CC + h * HD + e0;
            h8_t qa = *(const h8_t*)qp;
            h8_t qb = *(const h8_t*)(qp + 8);
            h8_t r0v, r1v;
            float Sp = 0.f;
#pragma unroll
            for (int i = 0; i < 4; i++) {
                float xr = (float)qa[2 * i], xi = (float)qa[2 * i + 1];
                float cv = ct[i], sv = st[i];
                r0v[2 * i]     = (_Float16)(xr * cv - xi * sv);
                r0v[2 * i + 1] = (_Float16)(xr * sv + xi * cv);
                Sp += xr * ksums[e0 + 2 * i] + xi * ksums[e0 + 2 * i + 1];
            }
#pragma unroll
            for (int i = 0; i < 4; i++) {
                float xr = (float)qb[2 * i], xi = (float)qb[2 * i + 1];
                float cv = ct[4 + i], sv = st[4 + i];
                r1v[2 * i]     = (_Float16)(xr * cv - xi * sv);
                r1v[2 * i + 1] = (_Float16)(xr * sv + xi * cv);
                Sp += xr * ksums[e0 + 8 + 2 * i] + xi * ksums[e0 + 8 + 2 * i + 1];
            }
            *(h8_t*)&qs[dd][e0]     = r0v;
            *(h8_t*)&qs[dd][e0 + 8] = r1v;
            Sred[dd][t & 3] = Sp;
        }
        __syncthreads();
        if (t < 64) {
            float S = (Sred[t][0] + Sred[t][1] + Sred[t][2] + Sred[t][3]) * (1.f / 4096.f);
            zs[t] = 1.f / (S + 1e-6f);
        }
        __syncthreads();

        // MFMA: wave owns n-rows [wave*16, wave*16+16); K = d = 64
        f4_t acc[4] = {};
#pragma unroll
        for (int k0 = 0; k0 < 64; k0 += 32) {
            h8_t af = *(const h8_t*)&qs[wave * 16 + fr][k0 + fk];
#pragma unroll
            for (int et = 0; et < 4; et++) {
                h8_t bf = *(const h8_t*)&kvt[et * 16 + fr][k0 + fk];
                acc[et] = __builtin_amdgcn_mfma_f32_16x16x32_f16(af, bf, acc[et], 0, 0, 0);
            }
        }
        const int col = lane & 15, rr0 = (lane >> 4) * 4;
#pragma unroll
        for (int r = 0; r < 4; r++) {
            const int nrow = wave * 16 + rr0 + r;
            const float z = zs[nrow];
#pragma unroll
            for (int et = 0; et < 4; et++)
                attn[nrow][et * 16 + col] = (_Float16)(acc[et][r] * z);
        }
        __syncthreads();

        // conv + store (original coalesced mapping)
        float cacc[16];
#pragma unroll
        for (int i = 0; i < 16; i++) cacc[i] = 0.f;
#pragma unroll
        for (int dr = -1; dr <= 1; dr++) {
            const int rr = ri + dr;
            if (rr < 0 || rr >= 64) continue;
#pragma unroll
            for (int dc = -1; dc <= 1; dc++) {
                const int cc2 = ci + dc;
                if (cc2 < 0 || cc2 >= 64) continue;
                const _Float16* xp = xh + (size_t)(b * SEQ + rr * 64 + cc2) * CC + h * HD + e0;
                const float* wp = wsh + ((dr + 1) * 3 + (dc + 1)) * 64 + e0;
                h8_t xa = *(const h8_t*)xp;
                h8_t xb = *(const h8_t*)(xp + 8);
#pragma unroll
                for (int i = 0; i < 8; i++) {
                    cacc[i]     += (float)xa[i] * wp[i];
                    cacc[8 + i] += (float)xb[i] * wp[8 + i];
                }
            }
        }
        h8_t a0 = *(const h8_t*)&attn[dd][e0];
        h8_t a1 = *(const h8_t*)&attn[dd][e0 + 8];
        float* op = out + (size_t)(b * SEQ + pix) * CC + h * HD + e0;
#pragma unroll
        for (int i = 0; i < 8; i++) {
            op[i]     = (float)a0[i] + cacc[i]     + lbs[e0 + i];
            op[8 + i] = (float)a1[i] + cacc[8 + i] + lbs[e0 + 8 + i];
        }
        __syncthreads();
    }
}

extern "C" void kernel_launch(void* const* d_in, const int* in_sizes, int n_in,
                              void* d_out, int out_size, void* d_ws, size_t ws_size,
                              hipStream_t stream) {
    const float* x      = (const float*)d_in[0];
    const float* qk_w   = (const float*)d_in[1];
    const float* qk_b   = (const float*)d_in[2];
    const float* lepe_w = (const float*)d_in[3];
    const float* lepe_b = (const float*)d_in[4];
    float* out = (float*)d_out;

    char* ws = (char*)d_ws;
    size_t off = 0;
    auto alloc = [&](size_t bytes) {
        void* p = ws + off;
        off += (bytes + 255) & ~(size_t)255;
        return p;
    };
    _Float16* xh   = (_Float16*)alloc((size_t)NB * SEQ * CC * 2);
    _Float16* wt   = (_Float16*)alloc((size_t)1024 * 512 * 2);
    _Float16* qpre = (_Float16*)alloc((size_t)NB * SEQ * CC * 2);
    _Float16* kpre = (_Float16*)alloc((size_t)NB * SEQ * CC * 2);
    float* kv      = (float*)alloc((size_t)NB * NH * HD * HD * 4);
    float* ksum    = (float*)alloc((size_t)NB * NH * HD * 4);
    float* ctab    = (float*)alloc(64 * 128 * 4);
    float* stab    = (float*)alloc(64 * 128 * 4);

    // kv + ksum are contiguous in ws: single memset covers both
    hipMemsetAsync(kv, 0, (size_t)NB * NH * HD * HD * 4 + (((size_t)NB * NH * HD * 4 + 255) & ~(size_t)255), stream);
    cvt_x_kernel<<<32768, 256, 0, stream>>>(x, xh);
    cvt_w_kernel<<<2048, 256, 0, stream>>>(qk_w, wt);
    rope_tables_kernel<<<32, 256, 0, stream>>>(ctab, stab);
    gemm_qk<<<dim3(8, 512), 256, 0, stream>>>(xh, wt, qk_b, qpre, kpre);
    kv_kernel<<<NB * NH * NSPLIT, 256, 0, stream>>>(kpre, xh, ctab, stab, kv, ksum);
    out_kernel<<<NB * NH * 8, 256, 0, stream>>>(qpre, xh, ctab, stab, kv, ksum, lepe_w, lepe_b, out);
}

// Round 4
// 494.153 us; speedup vs baseline: 2.0621x; 1.0103x over previous
//
#include <hip/hip_runtime.h>
#include <cstdint>
#include <cstddef>

#define NB   16
#define SEQ  4096
#define CC   512
#define NH   8
#define HD   64
#define NSPLIT 8

typedef _Float16 h8_t  __attribute__((ext_vector_type(8)));
typedef _Float16 h4_t  __attribute__((ext_vector_type(4)));
typedef float    f4_t  __attribute__((ext_vector_type(4)));

typedef __attribute__((address_space(1))) const void gv_t;
typedef __attribute__((address_space(3))) void lv_t;

__device__ __forceinline__ void gload16(const void* g, void* l) {
    __builtin_amdgcn_global_load_lds((gv_t*)g, (lv_t*)l, 16, 0, 0);
}

// ---------------- convert x (fp32 -> fp16) ----------------
__global__ __launch_bounds__(256) void cvt_x_kernel(const float* __restrict__ x,
                                                    _Float16* __restrict__ xh) {
    const int idx = blockIdx.x * 256 + threadIdx.x;      // 8388608 threads, 4 elems each
    const f4_t v = ((const f4_t*)x)[idx];
    h4_t o;
    o[0] = (_Float16)v[0]; o[1] = (_Float16)v[1];
    o[2] = (_Float16)v[2]; o[3] = (_Float16)v[3];
    ((h4_t*)xh)[idx] = o;
}

// ---------------- convert + transpose W (512x1024 -> Wt[1024][512] fp16) ----------------
__global__ __launch_bounds__(256) void cvt_w_kernel(const float* __restrict__ w,
                                                    _Float16* __restrict__ wt) {
    const int idx = blockIdx.x * 256 + threadIdx.x;      // 524288
    const int n = idx >> 9, k = idx & 511;
    wt[idx] = (_Float16)w[k * 1024 + n];
}

// ---------------- rope tables: ang[i][j] = i * theta_j, i<64, j<128 ----------------
__global__ __launch_bounds__(256) void rope_tables_kernel(float* __restrict__ ctab,
                                                          float* __restrict__ stab) {
    const int idx = blockIdx.x * 256 + threadIdx.x;      // 8192
    const int i = idx >> 7, j = idx & 127;
    const float theta = expf(-(float)j * (9.2103403719761836f / 128.f)); // 10000^(-j/128)
    const float ang = (float)i * theta;
    ctab[idx] = cosf(ang);
    stab[idx] = sinf(ang);
}

// ---------------- GEMM: qk = x @ W + bias, epilogue elu+1, split q/k ----------------
// XCD-aware swizzle: the 8 bn-siblings of each A-panel land on ONE XCD (L2 reuse).
__global__ __launch_bounds__(256) void gemm_qk(const _Float16* __restrict__ xh,
                                               const _Float16* __restrict__ wt,
                                               const float* __restrict__ bias,
                                               _Float16* __restrict__ qpre,
                                               _Float16* __restrict__ kpre) {
    __shared__ _Float16 smem[2 * 128 * 32];        // As | Bs, linear (no pad: gload_lds dest)
    _Float16* As = smem;
    _Float16* Bs = smem + 128 * 32;

    const int tid  = threadIdx.x;
    const int wave = tid >> 6, lane = tid & 63;
    // XCD swizzle: hw%8 = XCD id (round-robin dispatch); give each XCD a
    // contiguous chunk of 512 logical blocks = 64 complete A-panels.
    const int hw = blockIdx.x;                     // 0..4095
    const int L  = (hw & 7) * 512 + (hw >> 3);
    const int bn = L & 7, bm = L >> 3;             // bn fast within logical order
    const int wm = (wave >> 1) * 64, wn = (wave & 1) * 64;
    const int fr = lane & 15, fk = (lane >> 4) * 8;

    const int c0 = wave * 2;
    const int srow = c0 * 16 + (lane >> 2);
    const int scol = (lane & 3) * 8;

    const _Float16* agp0 = xh + (size_t)(bm * 128 + srow) * CC + scol;
    const _Float16* agp1 = agp0 + (size_t)16 * CC;
    const _Float16* bgp0 = wt + (size_t)(bn * 128 + srow) * CC + scol;
    const _Float16* bgp1 = bgp0 + (size_t)16 * CC;
    _Float16* alds0 = As + c0 * 512;
    _Float16* alds1 = As + (c0 + 1) * 512;
    _Float16* blds0 = Bs + c0 * 512;
    _Float16* blds1 = Bs + (c0 + 1) * 512;

    f4_t acc[4][4] = {};

    for (int k0 = 0; k0 < CC; k0 += 32) {
        gload16(agp0 + k0, alds0);
        gload16(agp1 + k0, alds1);
        gload16(bgp0 + k0, blds0);
        gload16(bgp1 + k0, blds1);
        __syncthreads();
        h8_t af[4], bf[4];
#pragma unroll
        for (int mi = 0; mi < 4; mi++) af[mi] = *(const h8_t*)&As[(wm + mi * 16 + fr) * 32 + fk];
#pragma unroll
        for (int ni = 0; ni < 4; ni++) bf[ni] = *(const h8_t*)&Bs[(wn + ni * 16 + fr) * 32 + fk];
#pragma unroll
        for (int mi = 0; mi < 4; mi++)
#pragma unroll
            for (int ni = 0; ni < 4; ni++)
                acc[mi][ni] = __builtin_amdgcn_mfma_f32_16x16x32_f16(af[mi], bf[ni], acc[mi][ni], 0, 0, 0);
        __syncthreads();
    }

    const int r4 = (lane >> 4) * 4;
#pragma unroll
    for (int ni = 0; ni < 4; ni++) {
        const int col = bn * 128 + wn + ni * 16 + fr;
        const float bc = bias[col];
#pragma unroll
        for (int mi = 0; mi < 4; mi++) {
#pragma unroll
            for (int r = 0; r < 4; r++) {
                const int row = bm * 128 + wm + mi * 16 + r4 + r;
                float v = acc[mi][ni][r] + bc;
                v = v > 0.f ? v + 1.f : __expf(v);      // elu(v)+1
                if (col < CC) qpre[(size_t)row * CC + col] = (_Float16)v;
                else          kpre[(size_t)row * CC + col - CC] = (_Float16)v;
            }
        }
    }
}

// ---------------- kv[b][h][d][e] = (1/4096) sum_n k_rope[n][d] * v[n][e]  (MFMA) ----------------
// also fused: ksum[b][h][d] = sum_n k_pre[n][d]
// LDS tiles channel-major: Kt[d][n], Vt[e][n], fp16, row pad 72 (144B rows -> b128-optimal banks).
__global__ __launch_bounds__(256) void kv_kernel(const _Float16* __restrict__ kpre,
                                                 const _Float16* __restrict__ xh,
                                                 const float* __restrict__ ctab,
                                                 const float* __restrict__ stab,
                                                 float* __restrict__ kv,
                                                 float* __restrict__ ksum) {
    const int blk = blockIdx.x;
    const int s = blk & (NSPLIT - 1);
    const int bh = blk / NSPLIT;
    const int b = bh >> 3, h = bh & 7;
    const int t = threadIdx.x;
    const int wave = t >> 6, lane = t & 63;

    __shared__ _Float16 Kt[64][72];
    __shared__ _Float16 Vt[64][72];

    const int nn  = lane;             // n within tile
    const int ch0 = wave * 16;        // channel block owned by this wave (stage + output d-rows)
    const int pbase = h * 32 + (ch0 >> 1);
    const bool rowrope = (pbase < 128);
    const int jbase = pbase & 127;
    const int fr = lane & 15, fk = (lane >> 4) * 8;

    f4_t acc[4] = {};
    float ksp[16];
#pragma unroll
    for (int i = 0; i < 16; i++) ksp[i] = 0.f;

    for (int c0 = 0; c0 < SEQ / NSPLIT; c0 += 64) {
        const int n = s * (SEQ / NSPLIT) + c0 + nn;
        const int ri = n >> 6, ci = n & 63;
        const int ii = rowrope ? ri : ci;
        const float* ct = ctab + ii * 128 + jbase;
        const float* st = stab + ii * 128 + jbase;

        const _Float16* kp = kpre + (size_t)(b * SEQ + n) * CC + h * HD + ch0;
        h8_t ka = *(const h8_t*)kp;
        h8_t kb = *(const h8_t*)(kp + 8);
#pragma unroll
        for (int i = 0; i < 8; i++) { ksp[i] += (float)ka[i]; ksp[8 + i] += (float)kb[i]; }
#pragma unroll
        for (int i = 0; i < 4; i++) {
            float xr = (float)ka[2 * i], xi = (float)ka[2 * i + 1];
            float cv = ct[i], sv = st[i];
            Kt[ch0 + 2 * i][nn]     = (_Float16)(xr * cv - xi * sv);
            Kt[ch0 + 2 * i + 1][nn] = (_Float16)(xr * sv + xi * cv);
        }
#pragma unroll
        for (int i = 0; i < 4; i++) {
            float xr = (float)kb[2 * i], xi = (float)kb[2 * i + 1];
            float cv = ct[4 + i], sv = st[4 + i];
            Kt[ch0 + 8 + 2 * i][nn]     = (_Float16)(xr * cv - xi * sv);
            Kt[ch0 + 8 + 2 * i + 1][nn] = (_Float16)(xr * sv + xi * cv);
        }
        const _Float16* xp = xh + (size_t)(b * SEQ + n) * CC + h * HD + ch0;
        h8_t va = *(const h8_t*)xp;
        h8_t vb = *(const h8_t*)(xp + 8);
#pragma unroll
        for (int i = 0; i < 8; i++) { Vt[ch0 + i][nn] = va[i]; Vt[ch0 + 8 + i][nn] = vb[i]; }
        __syncthreads();

#pragma unroll
        for (int k0 = 0; k0 < 64; k0 += 32) {
            h8_t af = *(const h8_t*)&Kt[ch0 + fr][k0 + fk];
#pragma unroll
            for (int et = 0; et < 4; et++) {
                h8_t bf = *(const h8_t*)&Vt[et * 16 + fr][k0 + fk];
                acc[et] = __builtin_amdgcn_mfma_f32_16x16x32_f16(af, bf, acc[et], 0, 0, 0);
            }
        }
        __syncthreads();
    }

    // epilogue: acc tile (rows d = ch0 + (lane>>4)*4+r, cols e = et*16 + (lane&15))
    const int col = lane & 15, r0 = (lane >> 4) * 4;
    float* kvbase = kv + (size_t)bh * HD * HD;
#pragma unroll
    for (int et = 0; et < 4; et++)
#pragma unroll
        for (int r = 0; r < 4; r++)
            atomicAdd(&kvbase[(ch0 + r0 + r) * HD + et * 16 + col], acc[et][r] * (1.f / 4096.f));

    // ksum: wave lanes cover all n of this split for channels ch0..ch0+15
#pragma unroll
    for (int i = 0; i < 16; i++) {
        float v = ksp[i];
#pragma unroll
        for (int m = 32; m; m >>= 1) v += __shfl_xor(v, m);
        if (lane == 0) atomicAdd(&ksum[bh * HD + ch0 + i], v);
    }
}

// ---------------- out = z * (q_rope @ kv) + depthwise3x3(v) + lepe_bias  (MFMA) ----------------
__global__ __launch_bounds__(256) void out_kernel(const _Float16* __restrict__ qpre,
                                                  const _Float16* __restrict__ xh,
                                                  const float* __restrict__ ctab,
                                                  const float* __restrict__ stab,
                                                  const float* __restrict__ kv,
                                                  const float* __restrict__ ksum,
                                                  const float* __restrict__ lw,
                                                  const float* __restrict__ lb,
                                                  float* __restrict__ out) {
    const int blk = blockIdx.x;
    const int rg = blk & 7;
    const int bh = blk >> 3;
    const int b = bh >> 3, h = bh & 7;
    const int t = threadIdx.x;
    const int wave = t >> 6, lane = t & 63;

    __shared__ _Float16 qs[64][72];    // q_rope tile, [n][d]
    __shared__ _Float16 kvt[64][72];   // kv^T, [e][d]
    __shared__ _Float16 attn[64][72];  // z * (q_rope @ kv), [n][e]
    __shared__ float Sred[64][4];
    __shared__ float zs[64];
    __shared__ float ksums[64];
    __shared__ float wsh[9 * 64];
    __shared__ float lbs[64];

    const int dd = t >> 2, e0 = (t & 3) * 16;
    const int fr = lane & 15, fk = (lane >> 4) * 8;

    {   // stage kv^T (fp16) once
        const float* kvp = kv + ((size_t)bh * HD + dd) * HD + e0;
#pragma unroll
        for (int i = 0; i < 16; i++) kvt[e0 + i][dd] = (_Float16)kvp[i];
    }
    if (t < 64) { ksums[t] = ksum[bh * HD + t]; lbs[t] = lb[h * HD + t]; }
    for (int i = t; i < 576; i += 256) wsh[i] = lw[(i >> 6) * CC + h * HD + (i & 63)];
    __syncthreads();

    const int pbase = h * 32 + (e0 >> 1);
    const bool rowrope = (pbase < 128);
    const int jbase = pbase & 127;

    for (int c0 = 0; c0 < 512; c0 += 64) {
        const int pix = rg * 512 + c0 + dd;
        const int ri = pix >> 6, ci = pix & 63;
        {   // stage q_rope (fp16, row-major) + S partial
            const int ii = rowrope ? ri : ci;
            const float* ct = ctab + ii * 128 + jbase;
            const float* st = stab + ii * 128 + jbase;
            const _Float16* qp = qpre + (size_t)(b * SEQ + pix) * CC + h * HD + e0;
            h8_t qa = *(const h8_t*)qp;
            h8_t qb = *(const h8_t*)(qp + 8);
            h8_t r0v, r1v;
            float Sp = 0.f;
#pragma unroll
            for (int i = 0; i < 4; i++) {
                float xr = (float)qa[2 * i], xi = (float)qa[2 * i + 1];
                float cv = ct[i], sv = st[i];
                r0v[2 * i]     = (_Float16)(xr * cv - xi * sv);
                r0v[2 * i + 1] = (_Float16)(xr * sv + xi * cv);
                Sp += xr * ksums[e0 + 2 * i] + xi * ksums[e0 + 2 * i + 1];
            }
#pragma unroll
            for (int i = 0; i < 4; i++) {
                float xr = (float)qb[2 * i], xi = (float)qb[2 * i + 1];
                float cv = ct[4 + i], sv = st[4 + i];
                r1v[2 * i]     = (_Float16)(xr * cv - xi * sv);
                r1v[2 * i + 1] = (_Float16)(xr * sv + xi * cv);
                Sp += xr * ksums[e0 + 8 + 2 * i] + xi * ksums[e0 + 8 + 2 * i + 1];
            }
            *(h8_t*)&qs[dd][e0]     = r0v;
            *(h8_t*)&qs[dd][e0 + 8] = r1v;
            Sred[dd][t & 3] = Sp;
        }
        __syncthreads();
        if (t < 64) {
            float S = (Sred[t][0] + Sred[t][1] + Sred[t][2] + Sred[t][3]) * (1.f / 4096.f);
            zs[t] = 1.f / (S + 1e-6f);
        }
        __syncthreads();

        // MFMA: wave owns n-rows [wave*16, wave*16+16); K = d = 64
        f4_t acc[4] = {};
#pragma unroll
        for (int k0 = 0; k0 < 64; k0 += 32) {
            h8_t af = *(const h8_t*)&qs[wave * 16 + fr][k0 + fk];
#pragma unroll
            for (int et = 0; et < 4; et++) {
                h8_t bf = *(const h8_t*)&kvt[et * 16 + fr][k0 + fk];
                acc[et] = __builtin_amdgcn_mfma_f32_16x16x32_f16(af, bf, acc[et], 0, 0, 0);
            }
        }
        const int col = lane & 15, rr0 = (lane >> 4) * 4;
#pragma unroll
        for (int r = 0; r < 4; r++) {
            const int nrow = wave * 16 + rr0 + r;
            const float z = zs[nrow];
#pragma unroll
            for (int et = 0; et < 4; et++)
                attn[nrow][et * 16 + col] = (_Float16)(acc[et][r] * z);
        }
        __syncthreads();

        // conv + store (original coalesced mapping)
        float cacc[16];
#pragma unroll
        for (int i = 0; i < 16; i++) cacc[i] = 0.f;
#pragma unroll
        for (int dr = -1; dr <= 1; dr++) {
            const int rr = ri + dr;
            if (rr < 0 || rr >= 64) continue;
#pragma unroll
            for (int dc = -1; dc <= 1; dc++) {
                const int cc2 = ci + dc;
                if (cc2 < 0 || cc2 >= 64) continue;
                const _Float16* xp = xh + (size_t)(b * SEQ + rr * 64 + cc2) * CC + h * HD + e0;
                const float* wp = wsh + ((dr + 1) * 3 + (dc + 1)) * 64 + e0;
                h8_t xa = *(const h8_t*)xp;
                h8_t xb = *(const h8_t*)(xp + 8);
#pragma unroll
                for (int i = 0; i < 8; i++) {
                    cacc[i]     += (float)xa[i] * wp[i];
                    cacc[8 + i] += (float)xb[i] * wp[8 + i];
                }
            }
        }
        h8_t a0 = *(const h8_t*)&attn[dd][e0];
        h8_t a1 = *(const h8_t*)&attn[dd][e0 + 8];
        float* op = out + (size_t)(b * SEQ + pix) * CC + h * HD + e0;
#pragma unroll
        for (int i = 0; i < 8; i++) {
            op[i]     = (float)a0[i] + cacc[i]     + lbs[e0 + i];
            op[8 + i] = (float)a1[i] + cacc[8 + i] + lbs[e0 + 8 + i];
        }
        __syncthreads();
    }
}

extern "C" void kernel_launch(void* const* d_in, const int* in_sizes, int n_in,
                              void* d_out, int out_size, void* d_ws, size_t ws_size,
                              hipStream_t stream) {
    const float* x      = (const float*)d_in[0];
    const float* qk_w   = (const float*)d_in[1];
    const float* qk_b   = (const float*)d_in[2];
    const float* lepe_w = (const float*)d_in[3];
    const float* lepe_b = (const float*)d_in[4];
    float* out = (float*)d_out;

    char* ws = (char*)d_ws;
    size_t off = 0;
    auto alloc = [&](size_t bytes) {
        void* p = ws + off;
        off += (bytes + 255) & ~(size_t)255;
        return p;
    };
    _Float16* xh   = (_Float16*)alloc((size_t)NB * SEQ * CC * 2);
    _Float16* wt   = (_Float16*)alloc((size_t)1024 * 512 * 2);
    _Float16* qpre = (_Float16*)alloc((size_t)NB * SEQ * CC * 2);
    _Float16* kpre = (_Float16*)alloc((size_t)NB * SEQ * CC * 2);
    float* kv      = (float*)alloc((size_t)NB * NH * HD * HD * 4);
    float* ksum    = (float*)alloc((size_t)NB * NH * HD * 4);
    float* ctab    = (float*)alloc(64 * 128 * 4);
    float* stab    = (float*)alloc(64 * 128 * 4);

    // kv + ksum are contiguous in ws: single memset covers both
    hipMemsetAsync(kv, 0, (size_t)NB * NH * HD * HD * 4 + (((size_t)NB * NH * HD * 4 + 255) & ~(size_t)255), stream);
    cvt_x_kernel<<<32768, 256, 0, stream>>>(x, xh);
    cvt_w_kernel<<<2048, 256, 0, stream>>>(qk_w, wt);
    rope_tables_kernel<<<32, 256, 0, stream>>>(ctab, stab);
    gemm_qk<<<4096, 256, 0, stream>>>(xh, wt, qk_b, qpre, kpre);
    kv_kernel<<<NB * NH * NSPLIT, 256, 0, stream>>>(kpre, xh, ctab, stab, kv, ksum);
    out_kernel<<<NB * NH * 8, 256, 0, stream>>>(qpre, xh, ctab, stab, kv, ksum, lepe_w, lepe_b, out);
}